// Round 11
// baseline (164.992 us; speedup 1.0000x reference)
//
#include <hip/hip_runtime.h>
#include <hip/hip_bf16.h>
#include <cstdint>
#include <cstddef>

#define BB 16
#define TT 8192
#define DD 512
#define NHEAD 8
#define NKV 2
#define HD 64
#define KVD 128
#define SCALE 0.125f

#define RB 64                // enc rows per block
#define NCHUNK (TT / RB)     // 128
#define BK 32
#define NSTEP (DD / BK)      // 16

typedef __attribute__((ext_vector_type(8))) short bf16x8;
typedef __attribute__((ext_vector_type(4))) float f32x4;

// workspace float offsets (7.18 MB)
#define WS_Q      0                    // 16*512          = 8192
#define WS_WBT    8192                 // 131072 u16      = 65536 floats
#define WS_OPART  73728                // 16*128*8*64     = 1048576
#define WS_ML     1122304              // 16*128*8*2      = 32768
#define WS_H      1155072              // 16*1024         = 16384
#define WS_APART  1171456              // 16*16*2048      = 524288
#define WS_M2     1728512              // 8*16*512        = 65536

__device__ __forceinline__ ushort f2bf(float f) {
    uint u = __builtin_bit_cast(uint, f);
    u += 0x7fffu + ((u >> 16) & 1u);
    return (ushort)(u >> 16);
}
// v_cvt_pk_bf16_f32: lo16 = bf16(a), hi16 = bf16(b), RNE — 1 VALU instr
__device__ __forceinline__ uint cvtpk(float a, float b) {
    uint r;
    asm("v_cvt_pk_bf16_f32 %0, %1, %2" : "=v"(r) : "v"(a), "v"(b));
    return r;
}
__device__ __forceinline__ float bf1(ushort s) {
    return __builtin_bit_cast(float, (uint)s << 16);
}
__device__ __forceinline__ float bflo(uint u) {
    return __builtin_bit_cast(float, u << 16);
}
__device__ __forceinline__ float bfhi(uint u) {
    return __builtin_bit_cast(float, u & 0xffff0000u);
}
__device__ __forceinline__ void gload_lds16(const void* g, void* l) {
    __builtin_amdgcn_global_load_lds((const __attribute__((address_space(1))) uint32_t*)g,
                                     (__attribute__((address_space(3))) uint32_t*)l, 16, 0, 0);
}

// ---- K0: weight pre-pack (GLL-linear FRAG-MAJOR) + q projection ------------
// wbt4 ushort index G: s = G>>13 (K-step), r = G&8191, fid = r>>9,
//   lane = (r>>3)&63, e = r&7;
//   col = (fid>>2)*64 + (fid&3)*16 + (lane&15); k = s*32 + (lane>>4)*8 + e;
//   wbt4[G] = bf16(Wcat[k][col])   (Wcat = [Wk | Wv] columns 0..255)
// blocks 64..95: q = query @ Wq ; b=(x-64)>>1, half=(x-64)&1
__global__ __launch_bounds__(256) void k_prep(const float* __restrict__ Wk,
                                              const float* __restrict__ Wv,
                                              const float* __restrict__ query,
                                              const float* __restrict__ Wq,
                                              ushort* __restrict__ wbt4,
                                              float* __restrict__ wsq) {
    const int t = threadIdx.x;
    if (blockIdx.x < 64) {
        const int G0 = blockIdx.x * 2048 + t * 8;
        const int s = G0 >> 13, r = G0 & 8191;
        const int fid = r >> 9, lane = (r >> 3) & 63;
        const int col = (fid >> 2) * 64 + (fid & 3) * 16 + (lane & 15);
        const int kbase = s * 32 + (lane >> 4) * 8;
        const float* W = (col < KVD) ? (Wk + col) : (Wv + (col - KVD));
#pragma unroll
        for (int e = 0; e < 8; ++e)
            wbt4[G0 + e] = f2bf(W[(size_t)(kbase + e) * KVD]);
    } else {
        __shared__ float qrow[DD];
        const int x = blockIdx.x - 64;
        const int b = x >> 1, half = x & 1;
        qrow[t] = query[b * DD + t];
        qrow[t + 256] = query[b * DD + t + 256];
        __syncthreads();
        const int col = half * 256 + t;
        float a0 = 0.f;
#pragma unroll 8
        for (int d = 0; d < DD; ++d) a0 = fmaf(qrow[d], Wq[(size_t)d * DD + col], a0);
        wsq[b * DD + col] = a0;
    }
}

// ---- K2: MFMA K/V projection + flash-decode attention ----------------------
// grid (NCHUNK, BB), 512 thr = 8 waves (wm=w>>2 rows, wn=w&3 cols).
// Wave tile 32x64 -> acc 2x4 frags = 32 regs/thread (was 64): fits the 128
// cap of (512,4) with headroom (est ~95 total) -> 4 waves/SIMD, 2 blocks/CU,
// 16 waves/CU (was 12). A frag-major slot = kg*64+row (identity-mapped,
// conflict-free); B layout/wbt4 unchanged from r9.
__global__ __launch_bounds__(512, 4) void k_attn(const float* __restrict__ enc,
                                                 const ushort* __restrict__ wbt4,
                                                 const float* __restrict__ wsq,
                                                 float* __restrict__ o_part,
                                                 float* __restrict__ ml) {
    __shared__ __align__(16) char smem[40960];   // A0|A1 (4K) B0|B1 (16K); kvl [64][258] aliases
    __shared__ float sc[NHEAD * RB];             // 2 KB
    __shared__ float qs[DD];                     // 2 KB

    const int tid = threadIdx.x;
    const int chunk = blockIdx.x, b = blockIdx.y;
    const int lane = tid & 63, w = tid >> 6;
    const int wm = w >> 2, wn = w & 3;

    qs[tid] = wsq[b * DD + tid] * SCALE;

    char* const A0 = smem;
    char* const A1 = smem + 4096;
    char* const B0 = smem + 8192;
    char* const B1 = smem + 24576;
    ushort* const kvl = (ushort*)smem;           // [64][258] bf16 = 33024 B

    const float* encb = enc + ((size_t)b * TT + (size_t)chunk * RB) * DD;

    // A staging: thread -> slot = tid>>1 (row = slot&63, kg = slot>>6), half = tid&1
    const int aslot = tid >> 1, ahalf = tid & 1;
    const int arow = aslot & 63, akg = aslot >> 6;

    f32x4 acc[2][4];
#pragma unroll
    for (int i = 0; i < 2; ++i)
#pragma unroll
        for (int j = 0; j < 4; ++j) acc[i][j] = (f32x4){0.f, 0.f, 0.f, 0.f};

    float4 e0;

#define LOAD_ENC(ss)                                                                 \
    {                                                                                \
        e0 = *(const float4*)(encb + (size_t)arow * DD + (ss) * BK + akg * 8 +       \
                              ahalf * 4);                                            \
    }
#define WRITE_A(Abuf)                                                                \
    {                                                                                \
        uint2 u_;                                                                    \
        u_.x = cvtpk(e0.x, e0.y);                                                    \
        u_.y = cvtpk(e0.z, e0.w);                                                    \
        *(uint2*)((Abuf) + aslot * 16 + ahalf * 8) = u_;                             \
    }
#define GLL_B(Bbuf, ss)                                                              \
    {                                                                                \
        _Pragma("unroll") for (int j = 0; j < 2; ++j)                                \
            gload_lds16(wbt4 + (size_t)(ss) * 8192 + ((j * 8 + w) * 64 + lane) * 8,  \
                        (Bbuf) + (j * 8 + w) * 1024);                                \
    }

    // prologue
    LOAD_ENC(0);
    GLL_B(B0, 0);
    WRITE_A(A0);
    LOAD_ENC(1);

    for (int s = 0; s < NSTEP; ++s) {
        const int cur = s & 1;
        char* const Ac = cur ? A1 : A0;
        char* const Bc = cur ? B1 : B0;
        char* const An = cur ? A0 : A1;
        char* const Bn = cur ? B0 : B1;
        __syncthreads();                         // A[cur]/B[cur] staged & visible
        if (s + 1 < NSTEP) {
            GLL_B(Bn, s + 1);
            WRITE_A(An);                         // e0 holds step s+1
            if (s + 2 < NSTEP) LOAD_ENC(s + 2);
        }
        bf16x8 bfr[4], af[2];
#pragma unroll
        for (int nt = 0; nt < 4; ++nt)
            bfr[nt] = *(const bf16x8*)(Bc + ((wn * 4 + nt) * 64 + lane) * 16);
#pragma unroll
        for (int rt = 0; rt < 2; ++rt)
            af[rt] = *(const bf16x8*)(Ac + ((lane >> 4) * 64 + wm * 32 + rt * 16 +
                                            (lane & 15)) * 16);
#pragma unroll
        for (int rt = 0; rt < 2; ++rt)
#pragma unroll
            for (int nt = 0; nt < 4; ++nt)
                acc[rt][nt] = __builtin_amdgcn_mfma_f32_16x16x32_bf16(
                    af[rt], bfr[nt], acc[rt][nt], 0, 0, 0);
    }

    const int h = w, kvh = h >> 2;               // wave = head

    // ---- epilogue: acc -> kvl[64][258] (cols 0..127 K, 128..255 V) ----
    __syncthreads();                             // all MFMA LDS reads done
#pragma unroll
    for (int rt = 0; rt < 2; ++rt)
#pragma unroll
        for (int nt = 0; nt < 4; ++nt) {
            const int col = wn * 64 + nt * 16 + (lane & 15);
#pragma unroll
            for (int j = 0; j < 4; ++j) {
                const int row = wm * 32 + rt * 16 + (lane >> 4) * 4 + j;
                kvl[row * 258 + col] = f2bf(acc[rt][nt][j]);
            }
        }
    __syncthreads();

    // scores: wave w == head h; row = lane
    {
        const float* qh = qs + h * HD;
        const uint* kr = (const uint*)(kvl + lane * 258 + kvh * HD);
        float s0 = 0.f;
#pragma unroll
        for (int d2 = 0; d2 < 32; ++d2) {
            const uint u = kr[d2];
            s0 = fmaf(bflo(u), qh[2 * d2], s0);
            s0 = fmaf(bfhi(u), qh[2 * d2 + 1], s0);
        }
        sc[h * RB + lane] = s0;
    }
    __syncthreads();

    // softmax + PV (d = lane)
    {
        float mx = -1e30f;
#pragma unroll 8
        for (int r = 0; r < RB; ++r) mx = fmaxf(mx, sc[h * RB + r]);
        float l0 = 0.f, o0 = 0.f;
        const ushort* vcol = kvl + KVD + kvh * HD + lane;
#pragma unroll 4
        for (int r = 0; r < RB; ++r) {
            const float p = __expf(sc[h * RB + r] - mx);
            l0 += p;
            o0 = fmaf(p, bf1(vcol[r * 258]), o0);
        }
        const size_t base = ((size_t)b * NCHUNK + chunk) * NHEAD + h;
        o_part[base * HD + lane] = o0;
        if (lane == 0) { ml[base * 2] = mx; ml[base * 2 + 1] = l0; }
    }
#undef LOAD_ENC
#undef WRITE_A
#undef GLL_B
}

// ---- K3: combine chunk partials (warp-parallel two-pass, 128 chunks) -------
__global__ __launch_bounds__(512) void k_reduce(const float* __restrict__ o_part,
                                                const float* __restrict__ ml,
                                                const float* __restrict__ query,
                                                float* __restrict__ hvec) {
    __shared__ float sEl[NHEAD][NCHUNK];
    const int b = blockIdx.x, t = threadIdx.x;
    const int h = t >> 6, lane = t & 63;

    // pass 1: per-chunk (m,l); each lane handles chunks lane, lane+64
    const size_t ma_i = (((size_t)b * NCHUNK + lane) * NHEAD + h) * 2;
    const size_t mb_i = (((size_t)b * NCHUNK + lane + 64) * NHEAD + h) * 2;
    const float ma = ml[ma_i], la = ml[ma_i + 1];
    const float mb = ml[mb_i], lb = ml[mb_i + 1];
    float M = fmaxf(ma, mb);
#pragma unroll
    for (int off = 32; off >= 1; off >>= 1) M = fmaxf(M, __shfl_xor(M, off));
    const float ea = __expf(ma - M), eb = __expf(mb - M);
    float L = la * ea + lb * eb;
#pragma unroll
    for (int off = 32; off >= 1; off >>= 1) L += __shfl_xor(L, off);
    sEl[h][lane] = ea;
    sEl[h][lane + 64] = eb;
    __syncthreads();

    // pass 2: O_d = sum_i o_part[i][d] * e[i]
    float O = 0.f;
#pragma unroll 4
    for (int i = 0; i < NCHUNK; ++i) {
        const size_t base = ((size_t)b * NCHUNK + i) * NHEAD + h;
        O = fmaf(o_part[base * HD + lane], sEl[h][i], O);
    }
    hvec[b * 1024 + h * HD + lane] = O / L;
    hvec[b * 1024 + 512 + t] = query[b * DD + t];
}

// ---- K4: MLP1 partial GEMM h @ W1 (16-way i-split) -------------------------
__global__ __launch_bounds__(256) void k_mlp1(const float* __restrict__ hvec,
                                              const float* __restrict__ W1,
                                              float* __restrict__ apart) {
    const int jb = blockIdx.x, ib = blockIdx.y;
    const int j = jb * 256 + threadIdx.x;
    float acc[BB];
#pragma unroll
    for (int b = 0; b < BB; ++b) acc[b] = 0.f;
    for (int i0 = ib * 64; i0 < ib * 64 + 64; i0 += 4) {
        const float w0 = W1[(size_t)(i0 + 0) * 2048 + j];
        const float w1 = W1[(size_t)(i0 + 1) * 2048 + j];
        const float w2 = W1[(size_t)(i0 + 2) * 2048 + j];
        const float w3 = W1[(size_t)(i0 + 3) * 2048 + j];
#pragma unroll
        for (int b = 0; b < BB; ++b) {
            const float* hb = hvec + b * 1024 + i0;
            acc[b] = fmaf(hb[0], w0, acc[b]);
            acc[b] = fmaf(hb[1], w1, acc[b]);
            acc[b] = fmaf(hb[2], w2, acc[b]);
            acc[b] = fmaf(hb[3], w3, acc[b]);
        }
    }
#pragma unroll
    for (int b = 0; b < BB; ++b)
        apart[((size_t)ib * BB + b) * 2048 + j] = acc[b];
}

// ---- K5: fused SiLU + MLP2 partial GEMM (8-way j-split) --------------------
__global__ __launch_bounds__(256) void k_mlp2(const float* __restrict__ apart,
                                              const float* __restrict__ W2,
                                              float* __restrict__ m2part) {
    __shared__ float actl[256];
    const int jb = blockIdx.x, b = blockIdx.y, ib = blockIdx.z;
    const int t = threadIdx.x;
    {
        const int jglob = ib * 256 + t;
        float s = 0.f;
#pragma unroll
        for (int p = 0; p < 16; ++p) s += apart[((size_t)p * BB + b) * 2048 + jglob];
        actl[t] = s / (1.f + __expf(-s));
    }
    __syncthreads();
    const int d = jb * 256 + t;
    float acc = 0.f;
    for (int j0 = 0; j0 < 256; j0 += 4) {
        const int jg = ib * 256 + j0;
        acc = fmaf(actl[j0 + 0], W2[(size_t)(jg + 0) * 512 + d], acc);
        acc = fmaf(actl[j0 + 1], W2[(size_t)(jg + 1) * 512 + d], acc);
        acc = fmaf(actl[j0 + 2], W2[(size_t)(jg + 2) * 512 + d], acc);
        acc = fmaf(actl[j0 + 3], W2[(size_t)(jg + 3) * 512 + d], acc);
    }
    m2part[((size_t)ib * BB + b) * 512 + d] = acc;
}

// ---- K6: sum mlp2 partials -> out ------------------------------------------
__global__ __launch_bounds__(512) void k_out(const float* __restrict__ m2part,
                                             float* __restrict__ out) {
    const int b = blockIdx.x, t = threadIdx.x;
    float s = 0.f;
#pragma unroll
    for (int ib = 0; ib < 8; ++ib) s += m2part[((size_t)ib * BB + b) * 512 + t];
    out[b * DD + t] = s;
}

extern "C" void kernel_launch(void* const* d_in, const int* in_sizes, int n_in,
                              void* d_out, int out_size, void* d_ws, size_t ws_size,
                              hipStream_t stream) {
    const float* query = (const float*)d_in[0];
    const float* enc   = (const float*)d_in[1];
    const float* Wq    = (const float*)d_in[2];
    const float* Wk    = (const float*)d_in[3];
    const float* Wv    = (const float*)d_in[4];
    const float* W1    = (const float*)d_in[5];
    const float* W2    = (const float*)d_in[6];
    float* ws  = (float*)d_ws;
    float* out = (float*)d_out;
    ushort* wbt4 = (ushort*)(ws + WS_WBT);

    k_prep<<<dim3(96), dim3(256), 0, stream>>>(Wk, Wv, query, Wq, wbt4, ws + WS_Q);
    k_attn<<<dim3(NCHUNK, BB), dim3(512), 0, stream>>>(enc, wbt4, ws + WS_Q,
                                                       ws + WS_OPART, ws + WS_ML);
    k_reduce<<<dim3(BB), dim3(512), 0, stream>>>(ws + WS_OPART, ws + WS_ML, query, ws + WS_H);
    k_mlp1<<<dim3(8, 16), dim3(256), 0, stream>>>(ws + WS_H, W1, ws + WS_APART);
    k_mlp2<<<dim3(2, BB, 8), dim3(256), 0, stream>>>(ws + WS_APART, W2, ws + WS_M2);
    k_out<<<dim3(BB), dim3(512), 0, stream>>>(ws + WS_M2, out);
}

// Round 12
// 143.485 us; speedup vs baseline: 1.1499x; 1.1499x over previous
//
#include <hip/hip_runtime.h>
#include <hip/hip_bf16.h>
#include <cstdint>
#include <cstddef>

#define BB 16
#define TT 8192
#define DD 512
#define NHEAD 8
#define NKV 2
#define HD 64
#define KVD 128
#define SCALE 0.125f

#define RB 64                // enc rows per block
#define NCHUNK (TT / RB)     // 128
#define BK 32
#define NSTEP (DD / BK)      // 16

typedef __attribute__((ext_vector_type(8))) short bf16x8;
typedef __attribute__((ext_vector_type(4))) float f32x4;

// workspace float offsets (7.18 MB)
#define WS_Q      0                    // 16*512          = 8192
#define WS_WBT    8192                 // 131072 u16      = 65536 floats
#define WS_OPART  73728                // 16*128*8*64     = 1048576
#define WS_ML     1122304              // 16*128*8*2      = 32768
#define WS_H      1155072              // 16*1024         = 16384
#define WS_APART  1171456              // 16*16*2048      = 524288
#define WS_M2     1728512              // 8*16*512        = 65536

__device__ __forceinline__ ushort f2bf(float f) {
    uint u = __builtin_bit_cast(uint, f);
    u += 0x7fffu + ((u >> 16) & 1u);
    return (ushort)(u >> 16);
}
// v_cvt_pk_bf16_f32: lo16 = bf16(a), hi16 = bf16(b), RNE — 1 VALU instr
__device__ __forceinline__ uint cvtpk(float a, float b) {
    uint r;
    asm("v_cvt_pk_bf16_f32 %0, %1, %2" : "=v"(r) : "v"(a), "v"(b));
    return r;
}
__device__ __forceinline__ float bf1(ushort s) {
    return __builtin_bit_cast(float, (uint)s << 16);
}
__device__ __forceinline__ float bflo(uint u) {
    return __builtin_bit_cast(float, u << 16);
}
__device__ __forceinline__ float bfhi(uint u) {
    return __builtin_bit_cast(float, u & 0xffff0000u);
}

// ---- K0: weight pre-pack (FRAG-MAJOR) + q projection ------------------------
// wbt4 ushort index G: s = G>>13 (K-step), r = G&8191, fid = r>>9,
//   lane = (r>>3)&63, e = r&7;
//   col = (fid>>2)*64 + (fid&3)*16 + (lane&15); k = s*32 + (lane>>4)*8 + e;
//   wbt4[G] = bf16(Wcat[k][col])   (Wcat = [Wk | Wv] columns 0..255)
// blocks 64..95: q = query @ Wq ; b=(x-64)>>1, half=(x-64)&1
__global__ __launch_bounds__(256) void k_prep(const float* __restrict__ Wk,
                                              const float* __restrict__ Wv,
                                              const float* __restrict__ query,
                                              const float* __restrict__ Wq,
                                              ushort* __restrict__ wbt4,
                                              float* __restrict__ wsq) {
    const int t = threadIdx.x;
    if (blockIdx.x < 64) {
        const int G0 = blockIdx.x * 2048 + t * 8;
        const int s = G0 >> 13, r = G0 & 8191;
        const int fid = r >> 9, lane = (r >> 3) & 63;
        const int col = (fid >> 2) * 64 + (fid & 3) * 16 + (lane & 15);
        const int kbase = s * 32 + (lane >> 4) * 8;
        const float* W = (col < KVD) ? (Wk + col) : (Wv + (col - KVD));
#pragma unroll
        for (int e = 0; e < 8; ++e)
            wbt4[G0 + e] = f2bf(W[(size_t)(kbase + e) * KVD]);
    } else {
        __shared__ float qrow[DD];
        const int x = blockIdx.x - 64;
        const int b = x >> 1, half = x & 1;
        qrow[t] = query[b * DD + t];
        qrow[t + 256] = query[b * DD + t + 256];
        __syncthreads();
        const int col = half * 256 + t;
        float a0 = 0.f;
#pragma unroll 8
        for (int d = 0; d < DD; ++d) a0 = fmaf(qrow[d], Wq[(size_t)d * DD + col], a0);
        wsq[b * DD + col] = a0;
    }
}

// ---- K2: MFMA K/V projection + flash-decode attention ----------------------
// grid (NCHUNK, BB), 256 thr = 4 waves, block tile 64 rows x 256 cols, BK=32.
// r10 skeleton with: B in REGISTERS from L2 (no global_load_lds anywhere) so
// barriers need NO vmcnt drain — SYNC = lgkmcnt(0)+s_barrier; enc prefetched
// 2 steps deep (eA/eB reg sets), B 1 step deep (bfA/bfB). Compiler inserts
// counted vmcnt waits at use points; loads stay in flight across barriers.
// NO launch_bounds cap (spill history r3/r5/r7). LDS 37KB; est ~145 regs ->
// 3 waves/SIMD, 3 blocks/CU.
__global__ __launch_bounds__(256) void k_attn(const float* __restrict__ enc,
                                              const ushort* __restrict__ wbt4,
                                              const float* __restrict__ wsq,
                                              float* __restrict__ o_part,
                                              float* __restrict__ ml) {
    __shared__ __align__(16) char smem[33024];   // A0|A1 (4K each); kvl [64][258] aliases
    __shared__ float sc[NHEAD * RB];             // 2 KB
    __shared__ float qs[DD];                     // 2 KB

    const int tid = threadIdx.x;
    const int chunk = blockIdx.x, b = blockIdx.y;
    const int lane = tid & 63, w = tid >> 6;

    qs[tid] = wsq[b * DD + tid] * SCALE;
    qs[tid + 256] = wsq[b * DD + tid + 256] * SCALE;

    char* const A0 = smem;
    char* const A1 = smem + 4096;
    ushort* const kvl = (ushort*)smem;           // [64][258] bf16 = 33024 B

    const float* encb = enc + ((size_t)b * TT + (size_t)chunk * RB) * DD;
    const ushort* wfr = wbt4 + ((size_t)w * 256 + lane) * 8;   // frag (w*4+nt), +nt*512

    const int srow = (tid >> 6) * 16 + (tid & 15);   // staged row
    const int skb = ((tid >> 4) & 3) * 8;            // k offset within step

    f32x4 acc[4][4];
#pragma unroll
    for (int i = 0; i < 4; ++i)
#pragma unroll
        for (int j = 0; j < 4; ++j) acc[i][j] = (f32x4){0.f, 0.f, 0.f, 0.f};

    float4 eA0, eA1, eB0, eB1;
    bf16x8 bfA[4], bfB[4], af[4];

#define LOAD_E(E0, E1, ss)                                                           \
    {                                                                                \
        const float* p_ = encb + (size_t)srow * DD + (ss) * BK + skb;                \
        E0 = *(const float4*)p_;                                                     \
        E1 = *(const float4*)(p_ + 4);                                               \
    }
#define WRITE_A(Abuf, E0, E1)                                                        \
    {                                                                                \
        uint4 u_;                                                                    \
        u_.x = cvtpk(E0.x, E0.y);                                                    \
        u_.y = cvtpk(E0.z, E0.w);                                                    \
        u_.z = cvtpk(E1.x, E1.y);                                                    \
        u_.w = cvtpk(E1.z, E1.w);                                                    \
        *(uint4*)((Abuf) + tid * 16) = u_;                                           \
    }
#define LOAD_B(BF, ss)                                                               \
    {                                                                                \
        _Pragma("unroll") for (int nt = 0; nt < 4; ++nt)                             \
            BF[nt] = *(const bf16x8*)(wfr + (size_t)(ss) * 8192 + nt * 512);         \
    }
#define SYNC()                                                                       \
    {                                                                                \
        __builtin_amdgcn_sched_barrier(0);                                           \
        asm volatile("s_waitcnt lgkmcnt(0)" ::: "memory");                           \
        __builtin_amdgcn_s_barrier();                                                \
    }
#define MFMA_STEP(Ac, BF)                                                            \
    {                                                                                \
        _Pragma("unroll") for (int rt = 0; rt < 4; ++rt)                             \
            af[rt] = *(const bf16x8*)((Ac) + (rt * 64 + lane) * 16);                 \
        _Pragma("unroll") for (int rt = 0; rt < 4; ++rt)                             \
            _Pragma("unroll") for (int nt = 0; nt < 4; ++nt)                         \
                acc[rt][nt] = __builtin_amdgcn_mfma_f32_16x16x32_bf16(               \
                    af[rt], BF[nt], acc[rt][nt], 0, 0, 0);                           \
    }

    // prologue: e-set k holds enc(step k&1 pattern): eA=0, eB=1, then eA=2
    LOAD_E(eA0, eA1, 0);
    LOAD_B(bfA, 0);
    LOAD_E(eB0, eB1, 1);
    WRITE_A(A0, eA0, eA1);
    LOAD_E(eA0, eA1, 2);
    SYNC();                                      // A0 visible

#pragma unroll
    for (int s = 0; s < NSTEP; ++s) {
        char* const Ac = (s & 1) ? A1 : A0;
        char* const An = (s & 1) ? A0 : A1;
        if ((s & 1) == 0) {
            if (s + 1 < NSTEP) WRITE_A(An, eB0, eB1);        // enc(s+1), set B
            if (s + 3 < NSTEP) LOAD_E(eB0, eB1, s + 3);      // refill set B
            if (s + 1 < NSTEP) LOAD_B(bfB, s + 1);           // B(s+1)
            MFMA_STEP(Ac, bfA);
        } else {
            if (s + 1 < NSTEP) WRITE_A(An, eA0, eA1);        // enc(s+1), set A
            if (s + 3 < NSTEP) LOAD_E(eA0, eA1, s + 3);      // refill set A
            if (s + 1 < NSTEP) LOAD_B(bfA, s + 1);           // B(s+1)
            MFMA_STEP(Ac, bfB);
        }
        SYNC();                                  // An visible next iter; Ac reads done
    }

    const int h0 = w * 2;                        // this wave's two heads
    const int kvh = h0 >> 2;

    // ---- epilogue: acc -> kvl[64][258] (cols 0..127 K, 128..255 V) ----
    __syncthreads();                             // full drain before aliasing A bufs
#pragma unroll
    for (int rt = 0; rt < 4; ++rt)
#pragma unroll
        for (int nt = 0; nt < 4; ++nt) {
            const int col = w * 64 + nt * 16 + (lane & 15);
#pragma unroll
            for (int j = 0; j < 4; ++j) {
                const int row = rt * 16 + (lane >> 4) * 4 + j;
                kvl[row * 258 + col] = f2bf(acc[rt][nt][j]);
            }
        }
    __syncthreads();

    // scores for heads h0, h0+1 (row = lane)
    {
        const float* qh0 = qs + h0 * HD;
        const float* qh1 = qs + (h0 + 1) * HD;
        const uint* kr = (const uint*)(kvl + lane * 258 + kvh * HD);
        float s0 = 0.f, s1 = 0.f;
#pragma unroll
        for (int d2 = 0; d2 < 32; ++d2) {
            const uint u = kr[d2];
            const float klo = bflo(u), khi = bfhi(u);
            s0 = fmaf(klo, qh0[2 * d2], s0);
            s0 = fmaf(khi, qh0[2 * d2 + 1], s0);
            s1 = fmaf(klo, qh1[2 * d2], s1);
            s1 = fmaf(khi, qh1[2 * d2 + 1], s1);
        }
        sc[h0 * RB + lane] = s0;
        sc[(h0 + 1) * RB + lane] = s1;
    }
    __syncthreads();

    // softmax + PV (d = lane; both heads share V rows)
    {
        float mx0 = -1e30f, mx1 = -1e30f;
#pragma unroll 8
        for (int r = 0; r < RB; ++r) {
            mx0 = fmaxf(mx0, sc[h0 * RB + r]);
            mx1 = fmaxf(mx1, sc[(h0 + 1) * RB + r]);
        }
        float l0 = 0.f, l1 = 0.f, o0 = 0.f, o1 = 0.f;
        const ushort* vcol = kvl + KVD + kvh * HD + lane;
#pragma unroll 4
        for (int r = 0; r < RB; ++r) {
            const float vv = bf1(vcol[r * 258]);
            const float p0 = __expf(sc[h0 * RB + r] - mx0);
            const float p1 = __expf(sc[(h0 + 1) * RB + r] - mx1);
            l0 += p0; o0 = fmaf(p0, vv, o0);
            l1 += p1; o1 = fmaf(p1, vv, o1);
        }
        const size_t base0 = ((size_t)b * NCHUNK + chunk) * NHEAD + h0;
        o_part[base0 * HD + lane] = o0;
        o_part[(base0 + 1) * HD + lane] = o1;
        if (lane == 0) {
            ml[base0 * 2] = mx0; ml[base0 * 2 + 1] = l0;
            ml[(base0 + 1) * 2] = mx1; ml[(base0 + 1) * 2 + 1] = l1;
        }
    }
#undef LOAD_E
#undef WRITE_A
#undef LOAD_B
#undef SYNC
#undef MFMA_STEP
}

// ---- K3: combine chunk partials (warp-parallel two-pass, 128 chunks) -------
__global__ __launch_bounds__(512) void k_reduce(const float* __restrict__ o_part,
                                                const float* __restrict__ ml,
                                                const float* __restrict__ query,
                                                float* __restrict__ hvec) {
    __shared__ float sEl[NHEAD][NCHUNK];
    const int b = blockIdx.x, t = threadIdx.x;
    const int h = t >> 6, lane = t & 63;

    // pass 1: per-chunk (m,l); each lane handles chunks lane, lane+64
    const size_t ma_i = (((size_t)b * NCHUNK + lane) * NHEAD + h) * 2;
    const size_t mb_i = (((size_t)b * NCHUNK + lane + 64) * NHEAD + h) * 2;
    const float ma = ml[ma_i], la = ml[ma_i + 1];
    const float mb = ml[mb_i], lb = ml[mb_i + 1];
    float M = fmaxf(ma, mb);
#pragma unroll
    for (int off = 32; off >= 1; off >>= 1) M = fmaxf(M, __shfl_xor(M, off));
    const float ea = __expf(ma - M), eb = __expf(mb - M);
    float L = la * ea + lb * eb;
#pragma unroll
    for (int off = 32; off >= 1; off >>= 1) L += __shfl_xor(L, off);
    sEl[h][lane] = ea;
    sEl[h][lane + 64] = eb;
    __syncthreads();

    // pass 2: O_d = sum_i o_part[i][d] * e[i]
    float O = 0.f;
#pragma unroll 4
    for (int i = 0; i < NCHUNK; ++i) {
        const size_t base = ((size_t)b * NCHUNK + i) * NHEAD + h;
        O = fmaf(o_part[base * HD + lane], sEl[h][i], O);
    }
    hvec[b * 1024 + h * HD + lane] = O / L;
    hvec[b * 1024 + 512 + t] = query[b * DD + t];
}

// ---- K4: MLP1 partial GEMM h @ W1 (16-way i-split) -------------------------
__global__ __launch_bounds__(256) void k_mlp1(const float* __restrict__ hvec,
                                              const float* __restrict__ W1,
                                              float* __restrict__ apart) {
    const int jb = blockIdx.x, ib = blockIdx.y;
    const int j = jb * 256 + threadIdx.x;
    float acc[BB];
#pragma unroll
    for (int b = 0; b < BB; ++b) acc[b] = 0.f;
    for (int i0 = ib * 64; i0 < ib * 64 + 64; i0 += 4) {
        const float w0 = W1[(size_t)(i0 + 0) * 2048 + j];
        const float w1 = W1[(size_t)(i0 + 1) * 2048 + j];
        const float w2 = W1[(size_t)(i0 + 2) * 2048 + j];
        const float w3 = W1[(size_t)(i0 + 3) * 2048 + j];
#pragma unroll
        for (int b = 0; b < BB; ++b) {
            const float* hb = hvec + b * 1024 + i0;
            acc[b] = fmaf(hb[0], w0, acc[b]);
            acc[b] = fmaf(hb[1], w1, acc[b]);
            acc[b] = fmaf(hb[2], w2, acc[b]);
            acc[b] = fmaf(hb[3], w3, acc[b]);
        }
    }
#pragma unroll
    for (int b = 0; b < BB; ++b)
        apart[((size_t)ib * BB + b) * 2048 + j] = acc[b];
}

// ---- K5: fused SiLU + MLP2 partial GEMM (8-way j-split) --------------------
__global__ __launch_bounds__(256) void k_mlp2(const float* __restrict__ apart,
                                              const float* __restrict__ W2,
                                              float* __restrict__ m2part) {
    __shared__ float actl[256];
    const int jb = blockIdx.x, b = blockIdx.y, ib = blockIdx.z;
    const int t = threadIdx.x;
    {
        const int jglob = ib * 256 + t;
        float s = 0.f;
#pragma unroll
        for (int p = 0; p < 16; ++p) s += apart[((size_t)p * BB + b) * 2048 + jglob];
        actl[t] = s / (1.f + __expf(-s));
    }
    __syncthreads();
    const int d = jb * 256 + t;
    float acc = 0.f;
    for (int j0 = 0; j0 < 256; j0 += 4) {
        const int jg = ib * 256 + j0;
        acc = fmaf(actl[j0 + 0], W2[(size_t)(jg + 0) * 512 + d], acc);
        acc = fmaf(actl[j0 + 1], W2[(size_t)(jg + 1) * 512 + d], acc);
        acc = fmaf(actl[j0 + 2], W2[(size_t)(jg + 2) * 512 + d], acc);
        acc = fmaf(actl[j0 + 3], W2[(size_t)(jg + 3) * 512 + d], acc);
    }
    m2part[((size_t)ib * BB + b) * 512 + d] = acc;
}

// ---- K6: sum mlp2 partials -> out ------------------------------------------
__global__ __launch_bounds__(512) void k_out(const float* __restrict__ m2part,
                                             float* __restrict__ out) {
    const int b = blockIdx.x, t = threadIdx.x;
    float s = 0.f;
#pragma unroll
    for (int ib = 0; ib < 8; ++ib) s += m2part[((size_t)ib * BB + b) * 512 + t];
    out[b * DD + t] = s;
}

extern "C" void kernel_launch(void* const* d_in, const int* in_sizes, int n_in,
                              void* d_out, int out_size, void* d_ws, size_t ws_size,
                              hipStream_t stream) {
    const float* query = (const float*)d_in[0];
    const float* enc   = (const float*)d_in[1];
    const float* Wq    = (const float*)d_in[2];
    const float* Wk    = (const float*)d_in[3];
    const float* Wv    = (const float*)d_in[4];
    const float* W1    = (const float*)d_in[5];
    const float* W2    = (const float*)d_in[6];
    float* ws  = (float*)d_ws;
    float* out = (float*)d_out;
    ushort* wbt4 = (ushort*)(ws + WS_WBT);

    k_prep<<<dim3(96), dim3(256), 0, stream>>>(Wk, Wv, query, Wq, wbt4, ws + WS_Q);
    k_attn<<<dim3(NCHUNK, BB), dim3(256), 0, stream>>>(enc, wbt4, ws + WS_Q,
                                                       ws + WS_OPART, ws + WS_ML);
    k_reduce<<<dim3(BB), dim3(512), 0, stream>>>(ws + WS_OPART, ws + WS_ML, query, ws + WS_H);
    k_mlp1<<<dim3(8, 16), dim3(256), 0, stream>>>(ws + WS_H, W1, ws + WS_APART);
    k_mlp2<<<dim3(2, BB, 8), dim3(256), 0, stream>>>(ws + WS_APART, W2, ws + WS_M2);
    k_out<<<dim3(BB), dim3(512), 0, stream>>>(ws + WS_M2, out);
}